// Round 13
// baseline (394.314 us; speedup 1.0000x reference)
//
#include <hip/hip_runtime.h>
#include <stdint.h>

typedef short short8 __attribute__((ext_vector_type(8)));
typedef float floatx4 __attribute__((ext_vector_type(4)));
typedef float floatx16 __attribute__((ext_vector_type(16)));

#define M_TOK 8192
#define K_IN  4096
#define N_OUT 4096
#define NT    (K_IN / 64)

// ---------- bf16 helpers (manual, RNE) ----------
static __device__ __forceinline__ float bf2f(ushort u) {
    union { uint32_t u; float f; } v;
    v.u = ((uint32_t)u) << 16;
    return v.f;
}
static __device__ __forceinline__ ushort f2bf(float f) {
    union { float f; uint32_t u; } v;
    v.f = f;
    uint32_t u = v.u;
    uint32_t r = (u + 0x7FFFu + ((u >> 16) & 1u)) >> 16;
    return (ushort)r;
}

// ---------- mask element-width detection via the 2:4 invariant ----------
__global__ void detect_zero_kernel(int* __restrict__ flags) {
    if (threadIdx.x < 3) flags[1 + threadIdx.x] = 0;
}

__global__ __launch_bounds__(256) void detect_count_kernel(
    const unsigned char* __restrict__ mb, int* __restrict__ flags) {
    const ushort* mh = (const ushort*)mb;
    const unsigned int* mw = (const unsigned int*)mb;
    __shared__ int sh[3];
    if (threadIdx.x < 3) sh[threadIdx.x] = 0;
    __syncthreads();
    int s = blockIdx.x * 256 + threadIdx.x;      // 16384 samples
    int grp = s & 255;                           // rows < 1024: in-bounds at all widths
    int o   = (s * 97) & 4095;
    int c1 = 0, c2 = 0, c4 = 0;
    #pragma unroll
    for (int r = 0; r < 4; ++r) {
        size_t idx = (size_t)(4 * grp + r) * N_OUT + o;
        c1 += (mb[idx] != 0);
        c2 += (mh[idx] != 0);
        c4 += (mw[idx] != 0);
    }
    if (c1 != 2) atomicAdd(&sh[0], 1);
    if (c2 != 2) atomicAdd(&sh[1], 1);
    if (c4 != 2) atomicAdd(&sh[2], 1);
    __syncthreads();
    if (threadIdx.x == 0) {
        atomicAdd(&flags[1], sh[0]);
        atomicAdd(&flags[2], sh[1]);
        atomicAdd(&flags[3], sh[2]);
    }
}

__global__ void detect_final_kernel(int* __restrict__ flags) {
    if (threadIdx.x == 0) {
        int size = 4, best = flags[3];
        if (flags[2] < best) { size = 2; best = flags[2]; }
        if (flags[1] < best) { size = 1; }
        flags[0] = size;
    }
}

// ---------- x (f32) -> bf16 workspace ----------
__global__ __launch_bounds__(256) void convert_x_kernel(
    const float* __restrict__ xf, ushort* __restrict__ Xb) {
    const int total = M_TOK * K_IN;
    const int stride = gridDim.x * 256 * 8;
    for (int i = (blockIdx.x * 256 + threadIdx.x) * 8; i < total; i += stride) {
        floatx4 f0 = *(const floatx4*)&xf[i];
        floatx4 f1 = *(const floatx4*)&xf[i + 4];
        short8 v;
        #pragma unroll
        for (int j = 0; j < 4; ++j) v[j]     = (short)f2bf(f0[j]);
        #pragma unroll
        for (int j = 0; j < 4; ++j) v[4 + j] = (short)f2bf(f1[j]);
        *(short8*)&Xb[i] = v;
    }
}

// ---------- dequant + transpose:  Bt[o][i] = bf16( mask ? (q-8)*scale[o] : 0 ) ----------
__global__ __launch_bounds__(256) void dequant_kernel(
    const int* __restrict__ q, const void* __restrict__ maskp,
    const float* __restrict__ scales, ushort* __restrict__ Bt,
    const int* __restrict__ flagp) {
    const int msize = flagp[0];
    const int i0 = blockIdx.x * 64;      // in_f
    const int o0 = blockIdx.y * 64;      // out_f
    const int tid = threadIdx.x;
    const unsigned char* mb = (const unsigned char*)maskp;
    const ushort* mh = (const ushort*)maskp;
    const unsigned int* mi = (const unsigned int*)maskp;
    __shared__ ushort T[64][72];

    for (int p = 0; p < 16; ++p) {
        int idx = p * 256 + tid;
        int r = idx >> 6, c = idx & 63;
        size_t gi = (size_t)(i0 + r) * N_OUT + (o0 + c);
        bool m;
        if (msize == 1)      m = (mb[gi] != 0);
        else if (msize == 2) m = (mh[gi] != 0);
        else                 m = (mi[gi] != 0);
        float s = scales[o0 + c];
        float w = m ? (float)(q[gi] - 8) * s : 0.0f;
        T[r][c] = f2bf(w);
    }
    __syncthreads();
    for (int p = 0; p < 2; ++p) {
        int ol = p * 32 + (tid >> 3);
        int i8 = (tid & 7) * 8;
        short8 v;
        #pragma unroll
        for (int j = 0; j < 8; ++j) v[j] = (short)T[i8 + j][ol];
        *(short8*)&Bt[(size_t)(o0 + ol) * K_IN + i0 + i8] = v;
    }
}

// ---------- bf16 GEMM: 256x256, BK=64, 8 waves, 32x32x16 MFMA core ----------
// v13: v12's free-running tile pipeline (1 vmcnt gate + 1 barrier per K-tile)
// with the compute core switched 16x16x32 -> 32x32x16:
//   - 2x FLOP per MFMA instruction (32/tile/wave instead of 64) => halves
//     CU-level MFMA issue pressure (the invariant across the three ~308us
//     schedules), ceiling 2075 -> 2382 TF.
//   - identical LDS traffic: 24 ds_read_b128/tile/wave, conflict-free under
//     the same chunk^(row&7) swizzle (8 lanes per bank-quad exactly).
// Frags: lane reads A[blk*32+(lane&31)][((2ks+(lane>>5))^((lane&31)&7))*8].
// C/D (m74/m101): col=lane&31, row=(reg&3)+8*(reg>>2)+4*(lane>>5).
// Locality mapping (v11): per-XCD 8Mx4N sub-blocks; FETCH ~220MB.
#define GL2L16(gp, lbase)                                                      \
    __builtin_amdgcn_global_load_lds(                                          \
        (const __attribute__((address_space(1))) void*)(gp),                   \
        (__attribute__((address_space(3))) void*)(lbase), 16, 0, 0)

#define MFMA32(a, b, c) __builtin_amdgcn_mfma_f32_32x32x16_bf16(a, b, c, 0, 0, 0)

__global__ __launch_bounds__(512, 2) void gemm_kernel(
    const ushort* __restrict__ X,   // [M_TOK][K_IN] bf16 bits (workspace)
    const ushort* __restrict__ Bt,  // [N_OUT][K_IN] bf16 bits (workspace)
    float* __restrict__ Y) {        // [M_TOK][N_OUT] float32
    __shared__ ushort As0[256][64], As1[256][64];
    __shared__ ushort Bs0[256][64], Bs1[256][64];

    const int tid  = threadIdx.x;
    const int w    = tid >> 6;          // 0..7
    const int lane = tid & 63;

    // L2/L3 locality mapping (bijective over 512 blocks)
    const int r    = blockIdx.x >> 8;          // 0..1
    const int k    = blockIdx.x & 255;
    const int xcd  = k & 7;
    const int j    = k >> 3;                   // 0..31
    const int m_tile = r * 16 + (xcd & 1) * 8 + (j & 7);   // 0..31
    const int n_tile = (xcd >> 1) * 4 + (j >> 3);          // 0..15
    const int row0 = m_tile * 256;
    const int col0 = n_tile * 256;
    const int wm = w >> 2, wn = w & 3;  // per-wave C = 128x64

    floatx16 acc[4][2] = {};

    const int srow   = (w << 3) + (lane >> 3);
    const int schunk = (lane & 7) ^ (lane >> 3);
    const ushort* gA = X  + (size_t)(row0 + srow) * K_IN + schunk * 8;
    const ushort* gB = Bt + (size_t)(col0 + srow) * K_IN + schunk * 8;

    const int r32 = lane & 31, hi = lane >> 5;
    const int fxx = r32 & 7;

    // stage one 128-row half (h=0/1) of k-tile tt from gbase into buf
    #define STG(gbase, buf, h, tt)                                             \
        do {                                                                   \
            GL2L16(gbase + (size_t)((h) * 128) * K_IN + (size_t)(tt) * 64,     \
                   (char*)&buf[(h) * 128 + w * 8][0] + lane * 16);             \
            GL2L16(gbase + (size_t)((h) * 128 + 64) * K_IN + (size_t)(tt) * 64,\
                   (char*)&buf[(h) * 128 + 64 + w * 8][0] + lane * 16);        \
        } while (0)

    #define LD_A(dst, As_, KS)                                                 \
        _Pragma("unroll") for (int mb = 0; mb < 4; ++mb)                       \
            dst[mb] = *(const short8*)&As_[wm * 128 + mb * 32 + r32]           \
                          [((2 * (KS) + hi) ^ fxx) * 8];
    #define LD_B(dst, Bs_, KS)                                                 \
        _Pragma("unroll") for (int nb = 0; nb < 2; ++nb)                       \
            dst[nb] = *(const short8*)&Bs_[wn * 64 + nb * 32 + r32]            \
                          [((2 * (KS) + hi) ^ fxx) * 8];
    #define MM(a_, b_)                                                         \
        __builtin_amdgcn_s_setprio(1);                                         \
        _Pragma("unroll") for (int mb = 0; mb < 4; ++mb)                       \
            _Pragma("unroll") for (int nb = 0; nb < 2; ++nb)                   \
                acc[mb][nb] = MFMA32(a_[mb], b_[nb], acc[mb][nb]);             \
        __builtin_amdgcn_s_setprio(0);

    // one K-tile: stage next || 4 K-steps, frag double-buffered (1-step lookahead)
    #define TILE(As_, Bs_, STAGE_STMT)                                         \
        do {                                                                   \
            STAGE_STMT;                                                        \
            short8 aA[4], bA[2], aB[4], bB[2];                                 \
            LD_A(aA, As_, 0) LD_B(bA, Bs_, 0)                                  \
            LD_A(aB, As_, 1) LD_B(bB, Bs_, 1)                                  \
            MM(aA, bA)                                                         \
            LD_A(aA, As_, 2) LD_B(bA, Bs_, 2)                                  \
            MM(aB, bB)                                                         \
            LD_A(aB, As_, 3) LD_B(bB, Bs_, 3)                                  \
            MM(aA, bA)                                                         \
            MM(aB, bB)                                                         \
            asm volatile("s_waitcnt vmcnt(0)" ::: "memory");                   \
            __builtin_amdgcn_s_barrier();                                      \
            __builtin_amdgcn_sched_barrier(0);                                 \
        } while (0)

    // prologue: tile0 -> buf0, drained
    STG(gA, As0, 0, 0); STG(gA, As0, 1, 0);
    STG(gB, Bs0, 0, 0); STG(gB, Bs0, 1, 0);
    asm volatile("s_waitcnt vmcnt(0)" ::: "memory");
    __builtin_amdgcn_s_barrier();
    __builtin_amdgcn_sched_barrier(0);

    for (int i = 0; i < NT / 2; ++i) {
        const int t1 = 2 * i + 1, t2 = 2 * i + 2;
        const bool s2 = (t2 < NT);

        TILE(As0, Bs0,
             { STG(gA, As1, 0, t1); STG(gA, As1, 1, t1);
               STG(gB, Bs1, 0, t1); STG(gB, Bs1, 1, t1); });
        TILE(As1, Bs1,
             if (s2) { STG(gA, As0, 0, t2); STG(gA, As0, 1, t2);
                       STG(gB, Bs0, 0, t2); STG(gB, Bs0, 1, t2); });
    }

    // epilogue: 32x32 C/D layout col=lane&31, row=(reg&3)+8*(reg>>2)+4*hi
    #pragma unroll
    for (int mb = 0; mb < 4; ++mb)
        #pragma unroll
        for (int nb = 0; nb < 2; ++nb)
            #pragma unroll
            for (int reg = 0; reg < 16; ++reg) {
                int crow = (reg & 3) + 8 * (reg >> 2) + 4 * hi;
                int rr = row0 + wm * 128 + mb * 32 + crow;
                int cc = col0 + wn * 64 + nb * 32 + r32;
                Y[(size_t)rr * N_OUT + cc] = acc[mb][nb][reg];
            }
    #undef TILE
    #undef MM
    #undef LD_B
    #undef LD_A
    #undef STG
}

// ---------- slow correct fallback (only if ws too small) ----------
__global__ __launch_bounds__(256) void fallback_kernel(
    const float* __restrict__ xf, const int* __restrict__ q,
    const void* __restrict__ maskp, const float* __restrict__ scales,
    float* __restrict__ Y, const int* __restrict__ flagp) {
    const int msize = flagp[0];
    const int o = blockIdx.x * 256 + threadIdx.x;
    const int t = blockIdx.y;
    const unsigned char* mb = (const unsigned char*)maskp;
    const ushort* mh = (const ushort*)maskp;
    const unsigned int* mi = (const unsigned int*)maskp;
    float s = scales[o];
    float acc = 0.f;
    for (int i = 0; i < K_IN; ++i) {
        float x = bf2f(f2bf(xf[(size_t)t * K_IN + i]));
        size_t gi = (size_t)i * N_OUT + o;
        bool m;
        if (msize == 1)      m = (mb[gi] != 0);
        else if (msize == 2) m = (mh[gi] != 0);
        else                 m = (mi[gi] != 0);
        if (m) acc += x * bf2f(f2bf((float)(q[gi] - 8) * s));
    }
    Y[(size_t)t * N_OUT + o] = acc;
}

extern "C" void kernel_launch(void* const* d_in, const int* in_sizes, int n_in,
                              void* d_out, int out_size, void* d_ws, size_t ws_size,
                              hipStream_t stream) {
    const float* x      = (const float*)d_in[0];
    const int*   q      = (const int*)d_in[1];
    const void*  mask   = d_in[2];
    const float* scales = (const float*)d_in[3];
    float* y = (float*)d_out;

    const size_t BT_OFF = 64;
    const size_t XB_OFF = BT_OFF + (size_t)N_OUT * K_IN * 2;   // 64 + 32MB
    const size_t need   = XB_OFF + (size_t)M_TOK * K_IN * 2;   // + 64MB

    int* flags = (int*)d_ws;
    detect_zero_kernel<<<1, 64, 0, stream>>>(flags);
    detect_count_kernel<<<64, 256, 0, stream>>>(
        (const unsigned char*)mask, flags);
    detect_final_kernel<<<1, 64, 0, stream>>>(flags);

    if (ws_size >= need) {
        ushort* Bt = (ushort*)((char*)d_ws + BT_OFF);
        ushort* Xb = (ushort*)((char*)d_ws + XB_OFF);
        convert_x_kernel<<<4096, 256, 0, stream>>>(x, Xb);
        dequant_kernel<<<dim3(K_IN / 64, N_OUT / 64), 256, 0, stream>>>(
            q, mask, scales, Bt, flags);
        gemm_kernel<<<dim3((M_TOK / 256) * (N_OUT / 256)), 512, 0, stream>>>(
            Xb, Bt, y);
    } else {
        fallback_kernel<<<dim3(N_OUT / 256, M_TOK), 256, 0, stream>>>(
            x, q, mask, scales, y, flags);
    }
}

// Round 14
// 358.744 us; speedup vs baseline: 1.0992x; 1.0992x over previous
//
#include <hip/hip_runtime.h>
#include <stdint.h>

typedef short short8 __attribute__((ext_vector_type(8)));
typedef float floatx4 __attribute__((ext_vector_type(4)));

#define M_TOK 8192
#define K_IN  4096
#define N_OUT 4096
#define NT    (K_IN / 64)

// ---------- bf16 helpers (manual, RNE) ----------
static __device__ __forceinline__ float bf2f(ushort u) {
    union { uint32_t u; float f; } v;
    v.u = ((uint32_t)u) << 16;
    return v.f;
}
static __device__ __forceinline__ ushort f2bf(float f) {
    union { float f; uint32_t u; } v;
    v.f = f;
    uint32_t u = v.u;
    uint32_t r = (u + 0x7FFFu + ((u >> 16) & 1u)) >> 16;
    return (ushort)r;
}

// ---------- mask element-width detection via the 2:4 invariant ----------
__global__ void detect_zero_kernel(int* __restrict__ flags) {
    if (threadIdx.x < 3) flags[1 + threadIdx.x] = 0;
}

__global__ __launch_bounds__(256) void detect_count_kernel(
    const unsigned char* __restrict__ mb, int* __restrict__ flags) {
    const ushort* mh = (const ushort*)mb;
    const unsigned int* mw = (const unsigned int*)mb;
    __shared__ int sh[3];
    if (threadIdx.x < 3) sh[threadIdx.x] = 0;
    __syncthreads();
    int s = blockIdx.x * 256 + threadIdx.x;      // 16384 samples
    int grp = s & 255;                           // rows < 1024: in-bounds at all widths
    int o   = (s * 97) & 4095;
    int c1 = 0, c2 = 0, c4 = 0;
    #pragma unroll
    for (int r = 0; r < 4; ++r) {
        size_t idx = (size_t)(4 * grp + r) * N_OUT + o;
        c1 += (mb[idx] != 0);
        c2 += (mh[idx] != 0);
        c4 += (mw[idx] != 0);
    }
    if (c1 != 2) atomicAdd(&sh[0], 1);
    if (c2 != 2) atomicAdd(&sh[1], 1);
    if (c4 != 2) atomicAdd(&sh[2], 1);
    __syncthreads();
    if (threadIdx.x == 0) {
        atomicAdd(&flags[1], sh[0]);
        atomicAdd(&flags[2], sh[1]);
        atomicAdd(&flags[3], sh[2]);
    }
}

__global__ void detect_final_kernel(int* __restrict__ flags) {
    if (threadIdx.x == 0) {
        int size = 4, best = flags[3];
        if (flags[2] < best) { size = 2; best = flags[2]; }
        if (flags[1] < best) { size = 1; }
        flags[0] = size;
    }
}

// ---------- x (f32) -> bf16 workspace ----------
__global__ __launch_bounds__(256) void convert_x_kernel(
    const float* __restrict__ xf, ushort* __restrict__ Xb) {
    const int total = M_TOK * K_IN;
    const int stride = gridDim.x * 256 * 8;
    for (int i = (blockIdx.x * 256 + threadIdx.x) * 8; i < total; i += stride) {
        floatx4 f0 = *(const floatx4*)&xf[i];
        floatx4 f1 = *(const floatx4*)&xf[i + 4];
        short8 v;
        #pragma unroll
        for (int j = 0; j < 4; ++j) v[j]     = (short)f2bf(f0[j]);
        #pragma unroll
        for (int j = 0; j < 4; ++j) v[4 + j] = (short)f2bf(f1[j]);
        *(short8*)&Xb[i] = v;
    }
}

// ---------- dequant + transpose:  Bt[o][i] = bf16( mask ? (q-8)*scale[o] : 0 ) ----------
__global__ __launch_bounds__(256) void dequant_kernel(
    const int* __restrict__ q, const void* __restrict__ maskp,
    const float* __restrict__ scales, ushort* __restrict__ Bt,
    const int* __restrict__ flagp) {
    const int msize = flagp[0];
    const int i0 = blockIdx.x * 64;      // in_f
    const int o0 = blockIdx.y * 64;      // out_f
    const int tid = threadIdx.x;
    const unsigned char* mb = (const unsigned char*)maskp;
    const ushort* mh = (const ushort*)maskp;
    const unsigned int* mi = (const unsigned int*)maskp;
    __shared__ ushort T[64][72];

    for (int p = 0; p < 16; ++p) {
        int idx = p * 256 + tid;
        int r = idx >> 6, c = idx & 63;
        size_t gi = (size_t)(i0 + r) * N_OUT + (o0 + c);
        bool m;
        if (msize == 1)      m = (mb[gi] != 0);
        else if (msize == 2) m = (mh[gi] != 0);
        else                 m = (mi[gi] != 0);
        float s = scales[o0 + c];
        float w = m ? (float)(q[gi] - 8) * s : 0.0f;
        T[r][c] = f2bf(w);
    }
    __syncthreads();
    for (int p = 0; p < 2; ++p) {
        int ol = p * 32 + (tid >> 3);
        int i8 = (tid & 7) * 8;
        short8 v;
        #pragma unroll
        for (int j = 0; j < 8; ++j) v[j] = (short)T[i8 + j][ol];
        *(short8*)&Bt[(size_t)(o0 + ol) * K_IN + i0 + i8] = v;
    }
}

// ---------- bf16 GEMM: 256x256, BK=64, 8 waves, deep-prefetch K-half ledger ----------
// v14: units = K-HALVES (256 rows x 32 k, contiguous [buf][kh][256][32] LDS).
// Phase order (mh0,k0),(mh1,k0),(mh0,k1),(mh1,k1): a K-half's last reader
// finishes 2 phases into the tile -> restageable mid-tile (row-halves never
// free mid-tile; that was v10's race). Ledger (slot-verified, incl. tails):
//   p1:(T+1).A.k1  p2:(T+1).B.k1  p3:(T+2).A.k0  p4:(T+2).B.k0 [gate v4]
//   p5:(T+2).A.k1  p6:(T+2).B.k1  p7:(T+3).A.k0  p8:(T+3).B.k0 [gate v4]
// Every stage-target freed >=1 barrier earlier; every read's unit drained by
// an intervening vmcnt gate; stages have 4-7 phases of latency slack.
// Swizzle (64B rows): LDS chunk c = G ^ ((row>>1)&3); write side
// (lane&3)^((lane>>3)&3); read side g^((fr>>1)&3). 8 words/bank balanced.
#define GL2L16(gp, lbase)                                                      \
    __builtin_amdgcn_global_load_lds(                                          \
        (const __attribute__((address_space(1))) void*)(gp),                   \
        (__attribute__((address_space(3))) void*)(lbase), 16, 0, 0)

__global__ __launch_bounds__(512, 2) void gemm_kernel(
    const ushort* __restrict__ X,   // [M_TOK][K_IN] bf16 bits (workspace)
    const ushort* __restrict__ Bt,  // [N_OUT][K_IN] bf16 bits (workspace)
    float* __restrict__ Y) {        // [M_TOK][N_OUT] float32
    __shared__ ushort As[2][2][256][32];   // [buf][khalf][row][k] 64 KiB
    __shared__ ushort Bs[2][2][256][32];   // 64 KiB

    const int tid  = threadIdx.x;
    const int w    = tid >> 6;          // 0..7
    const int lane = tid & 63;

    // L2/L3 locality mapping (bijective over 512 blocks)
    const int r    = blockIdx.x >> 8;          // 0..1
    const int kb   = blockIdx.x & 255;
    const int xcd  = kb & 7;
    const int j    = kb >> 3;                  // 0..31
    const int m_tile = r * 16 + (xcd & 1) * 8 + (j & 7);   // 0..31
    const int n_tile = (xcd >> 1) * 4 + (j >> 3);          // 0..15
    const int row0 = m_tile * 256;
    const int col0 = n_tile * 256;
    const int wm = w >> 2, wn = w & 3;  // per-wave C = 128x64

    floatx4 acc[8][4] = {};

    // staging map: load l covers rows l*128 + w*16 + (lane>>2); 4 lanes/row,
    // source chunk G = (lane&3)^((lane>>3)&3)  (inverse of LDS swizzle).
    const int srow   = (w << 4) + (lane >> 2);
    const int schunk = (lane & 3) ^ ((lane >> 3) & 3);
    const ushort* gA = X  + (size_t)(row0 + srow) * K_IN + schunk * 8;
    const ushort* gB = Bt + (size_t)(col0 + srow) * K_IN + schunk * 8;

    const int fr = lane & 15, g = lane >> 4;
    const int fsw = (fr >> 1) & 3;

    // stage one K-half unit (256 rows x 32 k) of tile tt into arr[bf][kh]
    #define STG(gbase, arr, bf, kh, tt)                                        \
        do {                                                                   \
            GL2L16(gbase + (size_t)(tt) * 64 + (kh) * 32,                      \
                   (char*)&arr[bf][kh][w * 16][0] + lane * 16);                \
            GL2L16(gbase + (size_t)128 * K_IN + (size_t)(tt) * 64 + (kh) * 32, \
                   (char*)&arr[bf][kh][128 + w * 16][0] + lane * 16);          \
        } while (0)

    // one phase: reads || stage ; BAR ; lgkm(0) ; 16 MFMA ; gate? ; BAR
    #define PHASE(BF, KK, MH, READB, bfr, STAGE_STMT, GATE_STMT)               \
        do {                                                                   \
            if (READB) {                                                       \
                _Pragma("unroll")                                              \
                for (int n = 0; n < 4; ++n)                                    \
                    bfr[n] = *(const short8*)&Bs[BF][KK]                       \
                        [wn * 64 + n * 16 + fr][(g ^ fsw) * 8];                \
            }                                                                  \
            short8 afr[4];                                                     \
            _Pragma("unroll")                                                  \
            for (int m = 0; m < 4; ++m)                                        \
                afr[m] = *(const short8*)&As[BF][KK]                           \
                    [wm * 128 + (MH) * 64 + m * 16 + fr][(g ^ fsw) * 8];       \
            STAGE_STMT;                                                        \
            __builtin_amdgcn_s_barrier();                                      \
            asm volatile("s_waitcnt lgkmcnt(0)" ::: "memory");                 \
            __builtin_amdgcn_sched_barrier(0);                                 \
            __builtin_amdgcn_s_setprio(1);                                     \
            _Pragma("unroll")                                                  \
            for (int m = 0; m < 4; ++m)                                        \
                _Pragma("unroll")                                              \
                for (int n = 0; n < 4; ++n)                                    \
                    acc[(MH) * 4 + m][n] = __builtin_amdgcn_mfma_f32_16x16x32_bf16( \
                        afr[m], bfr[n], acc[(MH) * 4 + m][n], 0, 0, 0);        \
            __builtin_amdgcn_s_setprio(0);                                     \
            GATE_STMT;                                                         \
            __builtin_amdgcn_s_barrier();                                      \
        } while (0)

    #define GATE(c)                                                            \
        do {                                                                   \
            if (c) { asm volatile("s_waitcnt vmcnt(4)" ::: "memory"); }        \
            else   { asm volatile("s_waitcnt vmcnt(0)" ::: "memory"); }        \
        } while (0)

    // prologue: T0 all 4 units -> buf0; T1 k0 units -> buf1 (left in flight)
    STG(gA, As, 0, 0, 0);
    STG(gB, Bs, 0, 0, 0);
    STG(gA, As, 0, 1, 0);
    STG(gB, Bs, 0, 1, 0);
    STG(gA, As, 1, 0, 1);
    STG(gB, Bs, 1, 0, 1);
    asm volatile("s_waitcnt vmcnt(4)" ::: "memory");
    __builtin_amdgcn_s_barrier();

    short8 bfr0[4], bfr1[4];

    for (int i = 0; i < NT / 2; ++i) {
        const int t1 = 2 * i + 1, t2 = 2 * i + 2, t3 = 2 * i + 3;
        const bool s2 = (t2 < NT), s3 = (t3 < NT);

        // ---- tile 2i from buf0 ----
        PHASE(0, 0, 0, 1, bfr0, STG(gA, As, 1, 1, t1), );
        PHASE(0, 0, 1, 0, bfr0, STG(gB, Bs, 1, 1, t1), );
        PHASE(0, 1, 0, 1, bfr1, if (s2) STG(gA, As, 0, 0, t2), );
        PHASE(0, 1, 1, 0, bfr1, if (s2) STG(gB, Bs, 0, 0, t2), GATE(s2));

        // ---- tile 2i+1 from buf1 ----
        PHASE(1, 0, 0, 1, bfr0, if (s2) STG(gA, As, 0, 1, t2), );
        PHASE(1, 0, 1, 0, bfr0, if (s2) STG(gB, Bs, 0, 1, t2), );
        PHASE(1, 1, 0, 1, bfr1, if (s3) STG(gA, As, 1, 0, t3), );
        PHASE(1, 1, 1, 0, bfr1, if (s3) STG(gB, Bs, 1, 0, t3), GATE(s3));
    }

    // epilogue: C/D layout col=lane&15, row=(lane>>4)*4+reg (m89-verified)
    const int fq = lane >> 4;
    #pragma unroll
    for (int m = 0; m < 8; ++m)
        #pragma unroll
        for (int n = 0; n < 4; ++n)
            #pragma unroll
            for (int i = 0; i < 4; ++i) {
                int rr = row0 + wm * 128 + m * 16 + fq * 4 + i;
                int cc = col0 + wn * 64 + n * 16 + fr;
                Y[(size_t)rr * N_OUT + cc] = acc[m][n][i];
            }
    #undef GATE
    #undef PHASE
    #undef STG
}

// ---------- slow correct fallback (only if ws too small) ----------
__global__ __launch_bounds__(256) void fallback_kernel(
    const float* __restrict__ xf, const int* __restrict__ q,
    const void* __restrict__ maskp, const float* __restrict__ scales,
    float* __restrict__ Y, const int* __restrict__ flagp) {
    const int msize = flagp[0];
    const int o = blockIdx.x * 256 + threadIdx.x;
    const int t = blockIdx.y;
    const unsigned char* mb = (const unsigned char*)maskp;
    const ushort* mh = (const ushort*)maskp;
    const unsigned int* mi = (const unsigned int*)maskp;
    float s = scales[o];
    float acc = 0.f;
    for (int i = 0; i < K_IN; ++i) {
        float x = bf2f(f2bf(xf[(size_t)t * K_IN + i]));
        size_t gi = (size_t)i * N_OUT + o;
        bool m;
        if (msize == 1)      m = (mb[gi] != 0);
        else if (msize == 2) m = (mh[gi] != 0);
        else                 m = (mi[gi] != 0);
        if (m) acc += x * bf2f(f2bf((float)(q[gi] - 8) * s));
    }
    Y[(size_t)t * N_OUT + o] = acc;
}

extern "C" void kernel_launch(void* const* d_in, const int* in_sizes, int n_in,
                              void* d_out, int out_size, void* d_ws, size_t ws_size,
                              hipStream_t stream) {
    const float* x      = (const float*)d_in[0];
    const int*   q      = (const int*)d_in[1];
    const void*  mask   = d_in[2];
    const float* scales = (const float*)d_in[3];
    float* y = (float*)d_out;

    const size_t BT_OFF = 64;
    const size_t XB_OFF = BT_OFF + (size_t)N_OUT * K_IN * 2;   // 64 + 32MB
    const size_t need   = XB_OFF + (size_t)M_TOK * K_IN * 2;   // + 64MB

    int* flags = (int*)d_ws;
    detect_zero_kernel<<<1, 64, 0, stream>>>(flags);
    detect_count_kernel<<<64, 256, 0, stream>>>(
        (const unsigned char*)mask, flags);
    detect_final_kernel<<<1, 64, 0, stream>>>(flags);

    if (ws_size >= need) {
        ushort* Bt = (ushort*)((char*)d_ws + BT_OFF);
        ushort* Xb = (ushort*)((char*)d_ws + XB_OFF);
        convert_x_kernel<<<4096, 256, 0, stream>>>(x, Xb);
        dequant_kernel<<<dim3(K_IN / 64, N_OUT / 64), 256, 0, stream>>>(
            q, mask, scales, Bt, flags);
        gemm_kernel<<<dim3((M_TOK / 256) * (N_OUT / 256)), 512, 0, stream>>>(
            Xb, Bt, y);
    } else {
        fallback_kernel<<<dim3(N_OUT / 256, M_TOK), 256, 0, stream>>>(
            x, q, mask, scales, y, flags);
    }
}